// Round 7
// baseline (91.677 us; speedup 1.0000x reference)
//
#include <hip/hip_runtime.h>

// DenseByItems: out[b,k] = dot(V[items[b,k]], seq[b]) + B[items[b,k]]
// seq: [4096,128] f32, items: [4096,200] i32, V: [100000,128] f32, B: [100000,1] f32
//
// Round 7: address-throughput-wall attack.
//  - prefilter kernel buckets items into per-(slice,b) lists ONCE (was 8x ballot filter)
//  - main: MFMA scoring, flattened set-stream, depth-2 static pipeline, no LDS
//  - bf16 V/seq copies + XCD slicing retained (r4-r6, fixed the HBM wall)

#define BATCH 4096
#define KITEMS 200
#define DIM 128
#define NITEMS 100000
#define NSLICE 8
#define SLICE_ROWS (NITEMS / NSLICE)   // 12500
#define GB 16                          // b's per block in main
#define CAP 208                        // list capacity (>=200, multiple of 16)

typedef __attribute__((ext_vector_type(8))) short bf16x8;
typedef __attribute__((ext_vector_type(4))) float f32x4;

__device__ __forceinline__ unsigned short f2bf(float f) {
    unsigned u = __float_as_uint(f);
    u += 0x7fffu + ((u >> 16) & 1u);   // round-to-nearest-even
    return (unsigned short)(u >> 16);
}

// ---- K1: V -> Vh (bf16), seq -> seqh (bf16) --------------------------------
#define NV_VEC (NITEMS * DIM / 8)      // 1,600,000
#define NS_VEC (BATCH * DIM / 8)       // 65,536
__global__ __launch_bounds__(256) void convert_kernel(
    const float* __restrict__ V, const float* __restrict__ seq,
    unsigned short* __restrict__ Vh, unsigned short* __restrict__ seqh) {
    int i = blockIdx.x * 256 + threadIdx.x;
    const float4* src;
    uint4* dst;
    if (i < NV_VEC) {
        src = reinterpret_cast<const float4*>(V) + (size_t)i * 2;
        dst = reinterpret_cast<uint4*>(Vh) + i;
    } else {
        i -= NV_VEC;
        src = reinterpret_cast<const float4*>(seq) + (size_t)i * 2;
        dst = reinterpret_cast<uint4*>(seqh) + i;
    }
    const float4 a = src[0];
    const float4 b = src[1];
    union { unsigned short h[8]; uint4 u; } pk;
    pk.h[0] = f2bf(a.x); pk.h[1] = f2bf(a.y); pk.h[2] = f2bf(a.z); pk.h[3] = f2bf(a.w);
    pk.h[4] = f2bf(b.x); pk.h[5] = f2bf(b.y); pk.h[6] = f2bf(b.z); pk.h[7] = f2bf(b.w);
    *dst = pk.u;
}

// ---- K2: prefilter — bucket each b's items into per-slice lists ------------
// lists layout: [NSLICE][BATCH][CAP] of (item<<8)|k ; counts: [NSLICE][BATCH]
__global__ __launch_bounds__(256) void prefilter_kernel(
    const int* __restrict__ items,
    int* __restrict__ lists,
    int* __restrict__ counts) {
    const int b = blockIdx.x;
    const int t = threadIdx.x;
    __shared__ int cnt[NSLICE];
    if (t < NSLICE) cnt[t] = 0;
    __syncthreads();
    if (t < KITEMS) {
        const int it = items[(size_t)b * KITEMS + t];
        const int s = it / SLICE_ROWS;                 // 0..7 (compile-time divisor)
        const int pos = atomicAdd(&cnt[s], 1);         // order nondet; outputs invariant
        lists[((size_t)s * BATCH + b) * CAP + pos] = (it << 8) | t;
    }
    __syncthreads();
    if (t < NSLICE) counts[(size_t)t * BATCH + b] = cnt[t];
}

// ---- K3: main — MFMA scoring with depth-2 pipeline -------------------------
struct Stage {
    int lid, jbase, nb;
    bf16x8 Af0, Af1, Af2, Af3;
    bf16x8 Bf0, Bf1, Bf2, Bf3;
    int4 e4;
};

__device__ __forceinline__ int sel4(const int4& c, int i) {
    int v = c.x;
    v = (i == 1) ? c.y : v;
    v = (i == 2) ? c.z : v;
    v = (i == 3) ? c.w : v;
    return v;
}

__device__ __forceinline__ bool advance(int& lid, int& jbase, int& nb, const int4& c4) {
    jbase += 16;
    if (jbase < nb) return true;
    while (++lid < 4) {
        const int n = sel4(c4, lid);
        if (n > 0) { nb = n; jbase = 0; return true; }
    }
    return false;
}

__device__ __forceinline__ void load_stage(Stage& st, int lid, int jbase, int nb,
                                           int b0, int s, int sub, int gw,
                                           const unsigned short* __restrict__ Vh,
                                           const unsigned short* __restrict__ seqh,
                                           const int* __restrict__ lists) {
    st.lid = lid; st.jbase = jbase; st.nb = nb;
    const int b = b0 + lid;
    const size_t lbase = ((size_t)s * BATCH + b) * CAP;
    const int pos = jbase + sub;
    const int posc = (pos < nb) ? pos : (nb - 1);      // dup address for tail lanes
    const int e = lists[lbase + posc];
    const int it = e >> 8;
    const unsigned short* rowp = Vh + (size_t)it * DIM + gw * 8;
    st.Af0 = *reinterpret_cast<const bf16x8*>(rowp);
    st.Af1 = *reinterpret_cast<const bf16x8*>(rowp + 32);
    st.Af2 = *reinterpret_cast<const bf16x8*>(rowp + 64);
    st.Af3 = *reinterpret_cast<const bf16x8*>(rowp + 96);
    const unsigned short* sqp = seqh + (size_t)b * DIM + gw * 8;
    st.Bf0 = *reinterpret_cast<const bf16x8*>(sqp);
    st.Bf1 = *reinterpret_cast<const bf16x8*>(sqp + 32);
    st.Bf2 = *reinterpret_cast<const bf16x8*>(sqp + 64);
    st.Bf3 = *reinterpret_cast<const bf16x8*>(sqp + 96);
    st.e4 = *reinterpret_cast<const int4*>(lists + lbase + jbase + gw * 4);
}

__device__ __forceinline__ void compute_stage(const Stage& st, int b0, int sub, int gw,
                                              const float* __restrict__ Bias,
                                              float* __restrict__ out) {
    f32x4 acc = {0.f, 0.f, 0.f, 0.f};
    acc = __builtin_amdgcn_mfma_f32_16x16x32_bf16(st.Af0, st.Bf0, acc, 0, 0, 0);
    acc = __builtin_amdgcn_mfma_f32_16x16x32_bf16(st.Af1, st.Bf1, acc, 0, 0, 0);
    acc = __builtin_amdgcn_mfma_f32_16x16x32_bf16(st.Af2, st.Bf2, acc, 0, 0, 0);
    acc = __builtin_amdgcn_mfma_f32_16x16x32_bf16(st.Af3, st.Bf3, acc, 0, 0, 0);
    // D mapping (HW-verified): col=lane&15, row=(lane>>4)*4+reg.
    // Writer lanes sub==0 own rows gw*4+r -> list positions jbase+gw*4+r.
    if (sub == 0) {
        const int b = b0 + st.lid;
        const int pbase = st.jbase + gw * 4;
        #pragma unroll
        for (int r = 0; r < 4; ++r) {
            if (pbase + r < st.nb) {
                const int e = (&st.e4.x)[r];           // r is compile-time constant
                out[(size_t)b * KITEMS + (e & 0xff)] = acc[r] + Bias[e >> 8];
            }
        }
    }
}

__global__ __launch_bounds__(256, 4) void main_mfma2_kernel(
    const unsigned short* __restrict__ Vh,
    const unsigned short* __restrict__ seqh,
    const float* __restrict__ Bias,
    const int* __restrict__ lists,
    const int* __restrict__ counts,
    float* __restrict__ out) {
    const unsigned bid = blockIdx.x;
    const int s = bid & 7;      // slice == XCD id under round-robin dispatch (heuristic)
    const int g = bid >> 3;
    const int tid = threadIdx.x;
    const int lane = tid & 63;
    const int wv = tid >> 6;
    const int sub = lane & 15;
    const int gw = lane >> 4;
    const int b0 = g * GB + wv * 4;    // wave's first b (4 consecutive)

    const int4 c4 = *reinterpret_cast<const int4*>(counts + (size_t)s * BATCH + b0);

    int lid = -1, jbase = -16, nb = 0;
    if (!advance(lid, jbase, nb, c4)) return;

    Stage sA, sB;
    load_stage(sA, lid, jbase, nb, b0, s, sub, gw, Vh, seqh, lists);
    for (;;) {
        bool hasN = advance(lid, jbase, nb, c4);
        if (hasN) load_stage(sB, lid, jbase, nb, b0, s, sub, gw, Vh, seqh, lists);
        compute_stage(sA, b0, sub, gw, Bias, out);
        if (!hasN) break;
        hasN = advance(lid, jbase, nb, c4);
        if (hasN) load_stage(sA, lid, jbase, nb, b0, s, sub, gw, Vh, seqh, lists);
        compute_stage(sB, b0, sub, gw, Bias, out);
        if (!hasN) break;
    }
}

// ---- fallback (ws too small): r5-style fp32 sliced kernel ------------------
__global__ __launch_bounds__(256) void fallback_kernel(
    const float* __restrict__ seq, const int* __restrict__ items,
    const float* __restrict__ V, const float* __restrict__ Bias,
    float* __restrict__ out) {
    const unsigned bid = blockIdx.x;
    const int s = bid & 7;
    const int g = bid >> 3;
    const int lo = s * SLICE_ROWS, hi = lo + SLICE_ROWS;
    const int tid = threadIdx.x;
    const int lane = tid & 63;
    const int sub = lane & 15;
    const int gw = lane >> 4;
    const int gid = ((tid >> 6) << 2) + gw;
    const int b = g * GB + gid;

    __shared__ int s_list[GB][KITEMS];
    const int* itb = items + (size_t)b * KITEMS;
    int n = 0;
    #pragma unroll
    for (int r = 0; r < 13; ++r) {
        const int k = r * 16 + sub;
        int it = 0;
        bool pred = false;
        if (k < KITEMS) { it = itb[k]; pred = (it >= lo) & (it < hi); }
        const unsigned long long bal = __ballot(pred);
        const unsigned m16 = (unsigned)(bal >> (gw * 16)) & 0xffffu;
        if (pred) s_list[gid][n + __popc(m16 & ((1u << sub) - 1u))] = (it << 8) | k;
        n += __popc(m16);
    }
    const float4* seqr = reinterpret_cast<const float4*>(seq + (size_t)b * DIM);
    const float4 q0 = seqr[2 * sub];
    const float4 q1 = seqr[2 * sub + 1];
    float* outb = out + (size_t)b * KITEMS;
    for (int j = 0; j < n; ++j) {
        const int pk = s_list[gid][j];
        const int it = pk >> 8, k = pk & 0xff;
        const float4* vr = reinterpret_cast<const float4*>(V + (size_t)it * DIM);
        const float4 a0 = vr[2 * sub], a1 = vr[2 * sub + 1];
        float p = q0.x * a0.x + q0.y * a0.y + q0.z * a0.z + q0.w * a0.w
                + q1.x * a1.x + q1.y * a1.y + q1.z * a1.z + q1.w * a1.w;
        p += __shfl_xor(p, 1);
        p += __shfl_xor(p, 2);
        p += __shfl_xor(p, 4);
        p += __shfl_xor(p, 8);
        if (sub == 0) outb[k] = p + Bias[it];
    }
}

extern "C" void kernel_launch(void* const* d_in, const int* in_sizes, int n_in,
                              void* d_out, int out_size, void* d_ws, size_t ws_size,
                              hipStream_t stream) {
    const float* seq   = (const float*)d_in[0];
    const int*   items = (const int*)d_in[1];
    const float* V     = (const float*)d_in[2];
    const float* Bias  = (const float*)d_in[3];
    float*       out   = (float*)d_out;

    const size_t vh_bytes    = (size_t)NITEMS * DIM * 2;            // 25,600,000
    const size_t sh_bytes    = (size_t)BATCH * DIM * 2;             //  1,048,576
    const size_t lists_bytes = (size_t)NSLICE * BATCH * CAP * 4;    // 27,262,976
    const size_t counts_bytes= (size_t)NSLICE * BATCH * 4;          //    131,072
    const size_t need = vh_bytes + sh_bytes + lists_bytes + counts_bytes;
    const int grid_main = (BATCH / GB) * NSLICE;                    // 2048

    if (ws_size >= need) {
        char* ws = (char*)d_ws;
        unsigned short* Vh    = (unsigned short*)ws;
        unsigned short* seqh  = (unsigned short*)(ws + vh_bytes);
        int*            lists = (int*)(ws + vh_bytes + sh_bytes);
        int*            counts= (int*)(ws + vh_bytes + sh_bytes + lists_bytes);
        convert_kernel<<<dim3((NV_VEC + NS_VEC) / 256), dim3(256), 0, stream>>>(V, seq, Vh, seqh);
        prefilter_kernel<<<dim3(BATCH), dim3(256), 0, stream>>>(items, lists, counts);
        main_mfma2_kernel<<<dim3(grid_main), dim3(256), 0, stream>>>(Vh, seqh, Bias, lists, counts, out);
    } else {
        fallback_kernel<<<dim3(grid_main), dim3(256), 0, stream>>>(seq, items, V, Bias, out);
    }
}

// Round 8
// 56.642 us; speedup vs baseline: 1.6185x; 1.6185x over previous
//
#include <hip/hip_runtime.h>

// DenseByItems: out[b,k] = dot(V[items[b,k]], seq[b]) + B[items[b,k]]
// seq: [4096,128] f32, items: [4096,200] i32, V: [100000,128] f32, B: [100000,1] f32
//
// Round 8: r5 structure (best so far) + two targeted fixes:
//  - L2 prefetch-touch: each block streams its slice chunk through its own
//    XCD's L2 before gathering (bid&7 -> XCD round-robin, shared mapping)
//  - process loop unrolled x4 (4 gathers in flight per 16-lane group)

#define BATCH 4096
#define KITEMS 200
#define DIM 128
#define NITEMS 100000
#define NSLICE 8
#define SLICE_ROWS (NITEMS / NSLICE)   // 12500
#define GB 16                          // b's per block (one per 16-lane group)
#define SLICE_U4 (SLICE_ROWS * DIM / 8)  // 200000 uint4 per slice (bf16)
#define TOUCH_PB ((SLICE_U4 + (BATCH / GB) - 1) / (BATCH / GB))  // 782

__device__ __forceinline__ unsigned short f2bf(float f) {
    unsigned u = __float_as_uint(f);
    u += 0x7fffu + ((u >> 16) & 1u);   // round-to-nearest-even
    return (unsigned short)(u >> 16);
}

// ---- K1: V (fp32, 51.2 MB) -> Vh (bf16, 25.6 MB) in workspace --------------
__global__ __launch_bounds__(256) void convert_kernel(const float* __restrict__ V,
                                                      unsigned short* __restrict__ Vh) {
    const int i = blockIdx.x * 256 + threadIdx.x;  // one uint4 (8 bf16) per thread
    const float4* src = reinterpret_cast<const float4*>(V) + (size_t)i * 2;
    const float4 a = src[0];
    const float4 b = src[1];
    union { unsigned short h[8]; uint4 u; } pk;
    pk.h[0] = f2bf(a.x); pk.h[1] = f2bf(a.y); pk.h[2] = f2bf(a.z); pk.h[3] = f2bf(a.w);
    pk.h[4] = f2bf(b.x); pk.h[5] = f2bf(b.y); pk.h[6] = f2bf(b.z); pk.h[7] = f2bf(b.w);
    reinterpret_cast<uint4*>(Vh)[i] = pk.u;
}

__device__ __forceinline__ float dot_bf16(const float4& q0, const float4& q1, const uint4& c) {
    const float v0 = __uint_as_float(c.x << 16);
    const float v1 = __uint_as_float(c.x & 0xffff0000u);
    const float v2 = __uint_as_float(c.y << 16);
    const float v3 = __uint_as_float(c.y & 0xffff0000u);
    const float v4 = __uint_as_float(c.z << 16);
    const float v5 = __uint_as_float(c.z & 0xffff0000u);
    const float v6 = __uint_as_float(c.w << 16);
    const float v7 = __uint_as_float(c.w & 0xffff0000u);
    return q0.x * v0 + q0.y * v1 + q0.z * v2 + q0.w * v3
         + q1.x * v4 + q1.y * v5 + q1.z * v6 + q1.w * v7;
}

// ---- K2: main — group-per-b, sliced bf16 gather, L2 touch, unroll x4 -------
template <bool BF16>
__global__ __launch_bounds__(256) void main_kernel(
    const float* __restrict__ seq,           // [BATCH, DIM]
    const int* __restrict__ items,           // [BATCH, KITEMS]
    const float* __restrict__ V,             // [NITEMS, DIM] fp32
    const unsigned short* __restrict__ Vh,   // [NITEMS, DIM] bf16 (if BF16)
    const float* __restrict__ Bias,          // [NITEMS]
    float* __restrict__ out)                 // [BATCH, KITEMS]
{
    const unsigned bid = blockIdx.x;
    const int s = bid & 7;       // slice == XCD id under round-robin dispatch (perf heuristic)
    const int g = bid >> 3;      // 0..255
    const int lo = s * SLICE_ROWS;
    const int hi = lo + SLICE_ROWS;

    const int tid  = threadIdx.x;
    const int lane = tid & 63;
    const int sub  = lane & 15;                         // lane within its 16-group
    const int gw   = lane >> 4;                         // group index within wave (0..3)
    const int gid  = ((tid >> 6) << 2) + gw;            // group id in block (0..15)
    const int b    = g * GB + gid;                      // this group's batch row

    // ---- L2 warm: stream this block's chunk of the slice through this XCD's
    // L2 (12.5 KB/block; 256 blocks cover the 3.2 MB slice). Cache-warm only.
    if (BF16) {
        const uint4* vh4 = reinterpret_cast<const uint4*>(Vh) + (size_t)s * SLICE_U4;
        const int base = g * TOUCH_PB;
        unsigned ax = 0, ay = 0, az = 0, aw = 0;
        #pragma unroll
        for (int i = 0; i < 4; ++i) {                   // 4*256 = 1024 >= TOUCH_PB(782)
            const int off = i * 256 + tid;
            if (off < TOUCH_PB && base + off < SLICE_U4) {
                const uint4 v = vh4[base + off];
                ax ^= v.x; ay ^= v.y; az ^= v.z; aw ^= v.w;
            }
        }
        asm volatile("" :: "v"(ax), "v"(ay), "v"(az), "v"(aw));
    }

    // ---- filter: ballot compaction, no atomics, warp-synchronous ----
    __shared__ int s_list[GB][KITEMS];
    const int* itb = items + (size_t)b * KITEMS;
    int n = 0;
    #pragma unroll
    for (int r = 0; r < 13; ++r) {                      // 13*16 = 208 >= 200
        const int k = r * 16 + sub;
        int it = 0;
        bool pred = false;
        if (k < KITEMS) {
            it = itb[k];
            pred = (it >= lo) & (it < hi);
        }
        const unsigned long long bal = __ballot(pred);
        const unsigned m16 = (unsigned)(bal >> (gw * 16)) & 0xffffu;
        if (pred) {
            const int pos = n + __popc(m16 & ((1u << sub) - 1u));
            s_list[gid][pos] = (it << 8) | k;
        }
        n += __popc(m16);                               // uniform within the group
    }

    // ---- seq row in registers (fp32) ----
    const float4* seqr = reinterpret_cast<const float4*>(seq + (size_t)b * DIM);
    const float4 q0 = seqr[2 * sub];
    const float4 q1 = seqr[2 * sub + 1];

    float* outb = out + (size_t)b * KITEMS;

    // ---- process: unrolled x4 (4 gathers in flight per group) ----
    int j = 0;
    for (; j + 4 <= n; j += 4) {
        const int pk0 = s_list[gid][j + 0];
        const int pk1 = s_list[gid][j + 1];
        const int pk2 = s_list[gid][j + 2];
        const int pk3 = s_list[gid][j + 3];
        const int it0 = pk0 >> 8, k0 = pk0 & 0xff;
        const int it1 = pk1 >> 8, k1 = pk1 & 0xff;
        const int it2 = pk2 >> 8, k2 = pk2 & 0xff;
        const int it3 = pk3 >> 8, k3 = pk3 & 0xff;

        float p0, p1, p2, p3;
        if (BF16) {
            const uint4 c0 = reinterpret_cast<const uint4*>(Vh + (size_t)it0 * DIM)[sub];
            const uint4 c1 = reinterpret_cast<const uint4*>(Vh + (size_t)it1 * DIM)[sub];
            const uint4 c2 = reinterpret_cast<const uint4*>(Vh + (size_t)it2 * DIM)[sub];
            const uint4 c3 = reinterpret_cast<const uint4*>(Vh + (size_t)it3 * DIM)[sub];
            p0 = dot_bf16(q0, q1, c0);
            p1 = dot_bf16(q0, q1, c1);
            p2 = dot_bf16(q0, q1, c2);
            p3 = dot_bf16(q0, q1, c3);
        } else {
            const float4* v0p = reinterpret_cast<const float4*>(V + (size_t)it0 * DIM);
            const float4* v1p = reinterpret_cast<const float4*>(V + (size_t)it1 * DIM);
            const float4* v2p = reinterpret_cast<const float4*>(V + (size_t)it2 * DIM);
            const float4* v3p = reinterpret_cast<const float4*>(V + (size_t)it3 * DIM);
            const float4 a0 = v0p[2 * sub], a1 = v0p[2 * sub + 1];
            const float4 b0 = v1p[2 * sub], b1 = v1p[2 * sub + 1];
            const float4 c0 = v2p[2 * sub], c1 = v2p[2 * sub + 1];
            const float4 d0 = v3p[2 * sub], d1 = v3p[2 * sub + 1];
            p0 = q0.x*a0.x + q0.y*a0.y + q0.z*a0.z + q0.w*a0.w + q1.x*a1.x + q1.y*a1.y + q1.z*a1.z + q1.w*a1.w;
            p1 = q0.x*b0.x + q0.y*b0.y + q0.z*b0.z + q0.w*b0.w + q1.x*b1.x + q1.y*b1.y + q1.z*b1.z + q1.w*b1.w;
            p2 = q0.x*c0.x + q0.y*c0.y + q0.z*c0.z + q0.w*c0.w + q1.x*c1.x + q1.y*c1.y + q1.z*c1.z + q1.w*c1.w;
            p3 = q0.x*d0.x + q0.y*d0.y + q0.z*d0.z + q0.w*d0.w + q1.x*d1.x + q1.y*d1.y + q1.z*d1.z + q1.w*d1.w;
        }
        const float bias0 = Bias[it0];
        const float bias1 = Bias[it1];
        const float bias2 = Bias[it2];
        const float bias3 = Bias[it3];

        p0 += __shfl_xor(p0, 1);  p1 += __shfl_xor(p1, 1);
        p2 += __shfl_xor(p2, 1);  p3 += __shfl_xor(p3, 1);
        p0 += __shfl_xor(p0, 2);  p1 += __shfl_xor(p1, 2);
        p2 += __shfl_xor(p2, 2);  p3 += __shfl_xor(p3, 2);
        p0 += __shfl_xor(p0, 4);  p1 += __shfl_xor(p1, 4);
        p2 += __shfl_xor(p2, 4);  p3 += __shfl_xor(p3, 4);
        p0 += __shfl_xor(p0, 8);  p1 += __shfl_xor(p1, 8);
        p2 += __shfl_xor(p2, 8);  p3 += __shfl_xor(p3, 8);

        if (sub == 0) {
            outb[k0] = p0 + bias0;
            outb[k1] = p1 + bias1;
            outb[k2] = p2 + bias2;
            outb[k3] = p3 + bias3;
        }
    }
    for (; j < n; ++j) {
        const int pk = s_list[gid][j];
        const int it = pk >> 8, k = pk & 0xff;
        float p;
        if (BF16) {
            const uint4 c = reinterpret_cast<const uint4*>(Vh + (size_t)it * DIM)[sub];
            p = dot_bf16(q0, q1, c);
        } else {
            const float4* vr = reinterpret_cast<const float4*>(V + (size_t)it * DIM);
            const float4 a0 = vr[2 * sub], a1 = vr[2 * sub + 1];
            p = q0.x*a0.x + q0.y*a0.y + q0.z*a0.z + q0.w*a0.w
              + q1.x*a1.x + q1.y*a1.y + q1.z*a1.z + q1.w*a1.w;
        }
        const float bias = Bias[it];
        p += __shfl_xor(p, 1);
        p += __shfl_xor(p, 2);
        p += __shfl_xor(p, 4);
        p += __shfl_xor(p, 8);
        if (sub == 0) outb[k] = p + bias;
    }
}

extern "C" void kernel_launch(void* const* d_in, const int* in_sizes, int n_in,
                              void* d_out, int out_size, void* d_ws, size_t ws_size,
                              hipStream_t stream) {
    const float* seq   = (const float*)d_in[0];
    const int*   items = (const int*)d_in[1];
    const float* V     = (const float*)d_in[2];
    const float* Bias  = (const float*)d_in[3];
    float*       out   = (float*)d_out;

    const size_t vh_bytes = (size_t)NITEMS * DIM * sizeof(unsigned short);  // 25.6 MB
    const int grid = (BATCH / GB) * NSLICE;  // 2048

    if (ws_size >= vh_bytes) {
        unsigned short* Vh = (unsigned short*)d_ws;
        convert_kernel<<<dim3(NITEMS * DIM / 8 / 256), dim3(256), 0, stream>>>(V, Vh);
        main_kernel<true><<<dim3(grid), dim3(256), 0, stream>>>(seq, items, V, Vh, Bias, out);
    } else {
        main_kernel<false><<<dim3(grid), dim3(256), 0, stream>>>(seq, items, V, nullptr, Bias, out);
    }
}

// Round 9
// 46.569 us; speedup vs baseline: 1.9686x; 1.2163x over previous
//
#include <hip/hip_runtime.h>

// DenseByItems: out[b,k] = dot(V[items[b,k]], seq[b]) + B[items[b,k]]
// seq: [4096,128] f32, items: [4096,200] i32, V: [100000,128] f32, B: [100000,1] f32
//
// Round 9: latency-chain attack. Wave-per-b geometry (4 items in flight via
// the 4 16-lane quads) x unroll 2 = 8 outstanding gathers, serial depth ~3-4
// memory epochs (was ~12 in r5's group-per-b). bf16 V + XCD slice retained.

#define BATCH 4096
#define KITEMS 200
#define DIM 128
#define NITEMS 100000
#define NSLICE 8
#define SLICE_ROWS (NITEMS / NSLICE)   // 12500
#define WPB 4                          // waves per block == b's per block
#define CAP 208

__device__ __forceinline__ unsigned short f2bf(float f) {
    unsigned u = __float_as_uint(f);
    u += 0x7fffu + ((u >> 16) & 1u);   // round-to-nearest-even
    return (unsigned short)(u >> 16);
}

// ---- K1: V (fp32, 51.2 MB) -> Vh (bf16, 25.6 MB) in workspace --------------
__global__ __launch_bounds__(256) void convert_kernel(const float* __restrict__ V,
                                                      unsigned short* __restrict__ Vh) {
    const int i = blockIdx.x * 256 + threadIdx.x;  // one uint4 (8 bf16) per thread
    const float4* src = reinterpret_cast<const float4*>(V) + (size_t)i * 2;
    const float4 a = src[0];
    const float4 b = src[1];
    union { unsigned short h[8]; uint4 u; } pk;
    pk.h[0] = f2bf(a.x); pk.h[1] = f2bf(a.y); pk.h[2] = f2bf(a.z); pk.h[3] = f2bf(a.w);
    pk.h[4] = f2bf(b.x); pk.h[5] = f2bf(b.y); pk.h[6] = f2bf(b.z); pk.h[7] = f2bf(b.w);
    reinterpret_cast<uint4*>(Vh)[i] = pk.u;
}

__device__ __forceinline__ float dot_bf16(const float4& q0, const float4& q1, const uint4& c) {
    const float v0 = __uint_as_float(c.x << 16);
    const float v1 = __uint_as_float(c.x & 0xffff0000u);
    const float v2 = __uint_as_float(c.y << 16);
    const float v3 = __uint_as_float(c.y & 0xffff0000u);
    const float v4 = __uint_as_float(c.z << 16);
    const float v5 = __uint_as_float(c.z & 0xffff0000u);
    const float v6 = __uint_as_float(c.w << 16);
    const float v7 = __uint_as_float(c.w & 0xffff0000u);
    return q0.x * v0 + q0.y * v1 + q0.z * v2 + q0.w * v3
         + q1.x * v4 + q1.y * v5 + q1.z * v6 + q1.w * v7;
}

// ---- K2: main — wave-per-b, sliced bf16 gather -----------------------------
template <bool BF16>
__global__ __launch_bounds__(256, 8) void main_kernel(
    const float* __restrict__ seq,           // [BATCH, DIM]
    const int* __restrict__ items,           // [BATCH, KITEMS]
    const float* __restrict__ V,             // [NITEMS, DIM] fp32
    const unsigned short* __restrict__ Vh,   // [NITEMS, DIM] bf16 (if BF16)
    const float* __restrict__ Bias,          // [NITEMS]
    float* __restrict__ out)                 // [BATCH, KITEMS]
{
    const unsigned bid = blockIdx.x;
    const int s = bid & 7;       // slice == XCD id under round-robin dispatch (perf heuristic)
    const int g = bid >> 3;      // 0..1023
    const int lo = s * SLICE_ROWS;
    const int hi = lo + SLICE_ROWS;

    const int tid  = threadIdx.x;
    const int lane = tid & 63;
    const int wv   = tid >> 6;   // wave 0..3 -> which b
    const int sub  = lane & 15;  // lane within quad's 16-group
    const int qd   = lane >> 4;  // quad 0..3 -> which item slot
    const int b    = g * WPB + wv;

    __shared__ int s_list[WPB][CAP];   // wave-private compacted (item<<8)|k

    // ---- filter: 4 ballot rounds across the full wave ----
    const int* itb = items + (size_t)b * KITEMS;
    int n = 0;
    #pragma unroll
    for (int r = 0; r < 4; ++r) {                 // 4*64 = 256 >= 200
        const int k = r * 64 + lane;
        int it = 0;
        bool pred = false;
        if (k < KITEMS) {
            it = itb[k];
            pred = (it >= lo) & (it < hi);
        }
        const unsigned long long bal = __ballot(pred);
        if (pred) {
            const int pos = n + __popcll(bal & ((1ull << lane) - 1ull));
            s_list[wv][pos] = (it << 8) | k;
        }
        n += __popcll(bal);                       // uniform across the wave
    }
    if (n == 0) return;

    // ---- seq row in registers (all 4 quads share b; addresses replicate) ----
    const float4* seqr = reinterpret_cast<const float4*>(seq + (size_t)b * DIM);
    const float4 q0 = seqr[2 * sub];
    const float4 q1 = seqr[2 * sub + 1];
    float* outb = out + (size_t)b * KITEMS;

    // ---- process: 8 items per wave-iteration (4 quads x unroll 2) ----
    int t = 0;
    for (; t + 8 <= n; t += 8) {
        const int eA = s_list[wv][t + qd];
        const int eB = s_list[wv][t + 4 + qd];
        const int itA = eA >> 8, kA = eA & 0xff;
        const int itB = eB >> 8, kB = eB & 0xff;

        float pA, pB, biasA, biasB;
        if (BF16) {
            const uint4 cA = reinterpret_cast<const uint4*>(Vh + (size_t)itA * DIM)[sub];
            const uint4 cB = reinterpret_cast<const uint4*>(Vh + (size_t)itB * DIM)[sub];
            biasA = Bias[itA];
            biasB = Bias[itB];
            pA = dot_bf16(q0, q1, cA);
            pB = dot_bf16(q0, q1, cB);
        } else {
            const float4* vA = reinterpret_cast<const float4*>(V + (size_t)itA * DIM);
            const float4* vB = reinterpret_cast<const float4*>(V + (size_t)itB * DIM);
            const float4 a0 = vA[2 * sub], a1 = vA[2 * sub + 1];
            const float4 b0 = vB[2 * sub], b1 = vB[2 * sub + 1];
            biasA = Bias[itA];
            biasB = Bias[itB];
            pA = q0.x*a0.x + q0.y*a0.y + q0.z*a0.z + q0.w*a0.w + q1.x*a1.x + q1.y*a1.y + q1.z*a1.z + q1.w*a1.w;
            pB = q0.x*b0.x + q0.y*b0.y + q0.z*b0.z + q0.w*b0.w + q1.x*b1.x + q1.y*b1.y + q1.z*b1.z + q1.w*b1.w;
        }

        pA += __shfl_xor(pA, 1);  pB += __shfl_xor(pB, 1);
        pA += __shfl_xor(pA, 2);  pB += __shfl_xor(pB, 2);
        pA += __shfl_xor(pA, 4);  pB += __shfl_xor(pB, 4);
        pA += __shfl_xor(pA, 8);  pB += __shfl_xor(pB, 8);

        if (sub == 0) {
            outb[kA] = pA + biasA;
            outb[kB] = pB + biasB;
        }
    }
    // tail: < 8 items, quad-stride depth-1
    for (; t < n; t += 4) {
        const int i = t + qd;
        const bool act = i < n;
        const int e = s_list[wv][act ? i : (n - 1)];
        const int it = e >> 8, k = e & 0xff;
        float p, bias;
        if (BF16) {
            const uint4 c = reinterpret_cast<const uint4*>(Vh + (size_t)it * DIM)[sub];
            bias = Bias[it];
            p = dot_bf16(q0, q1, c);
        } else {
            const float4* vr = reinterpret_cast<const float4*>(V + (size_t)it * DIM);
            const float4 a0 = vr[2 * sub], a1 = vr[2 * sub + 1];
            bias = Bias[it];
            p = q0.x*a0.x + q0.y*a0.y + q0.z*a0.z + q0.w*a0.w
              + q1.x*a1.x + q1.y*a1.y + q1.z*a1.z + q1.w*a1.w;
        }
        p += __shfl_xor(p, 1);
        p += __shfl_xor(p, 2);
        p += __shfl_xor(p, 4);
        p += __shfl_xor(p, 8);
        if (act && sub == 0) outb[k] = p + bias;
    }
}

extern "C" void kernel_launch(void* const* d_in, const int* in_sizes, int n_in,
                              void* d_out, int out_size, void* d_ws, size_t ws_size,
                              hipStream_t stream) {
    const float* seq   = (const float*)d_in[0];
    const int*   items = (const int*)d_in[1];
    const float* V     = (const float*)d_in[2];
    const float* Bias  = (const float*)d_in[3];
    float*       out   = (float*)d_out;

    const size_t vh_bytes = (size_t)NITEMS * DIM * sizeof(unsigned short);  // 25.6 MB
    const int grid = (BATCH / WPB) * NSLICE;  // 8192

    if (ws_size >= vh_bytes) {
        unsigned short* Vh = (unsigned short*)d_ws;
        convert_kernel<<<dim3(NITEMS * DIM / 8 / 256), dim3(256), 0, stream>>>(V, Vh);
        main_kernel<true><<<dim3(grid), dim3(256), 0, stream>>>(seq, items, V, Vh, Bias, out);
    } else {
        main_kernel<false><<<dim3(grid), dim3(256), 0, stream>>>(seq, items, V, nullptr, Bias, out);
    }
}

// Round 10
// 44.948 us; speedup vs baseline: 2.0396x; 1.0361x over previous
//
#include <hip/hip_runtime.h>

// DenseByItems: out[b,k] = dot(V[items[b,k]], seq[b]) + B[items[b,k]]
// seq: [4096,128] f32, items: [4096,200] i32, V: [100000,128] f32, B: [100000,1] f32
//
// Round 10: address-rate-wall reduction.
//  - prep kernel = V->bf16 convert (6250 blocks) + per-(slice,b) prefilter
//    (4096 blocks) fused in one grid
//  - main: no filter, no LDS; <=64 list entries held in registers + __shfl
//    broadcast; bias/store predicated to 1 lane per item; bf16 V + XCD slice.

#define BATCH 4096
#define KITEMS 200
#define DIM 128
#define NITEMS 100000
#define NSLICE 8
#define SLICE_ROWS (NITEMS / NSLICE)   // 12500
#define CAP 208
#define NV_VEC (NITEMS * DIM / 8)      // 1,600,000 uint4
#define CONV_BLOCKS (NV_VEC / 256)     // 6250
#define PREP_BLOCKS (CONV_BLOCKS + BATCH)

__device__ __forceinline__ unsigned short f2bf(float f) {
    unsigned u = __float_as_uint(f);
    u += 0x7fffu + ((u >> 16) & 1u);   // round-to-nearest-even
    return (unsigned short)(u >> 16);
}

__device__ __forceinline__ float dot_bf16(const float4& q0, const float4& q1, const uint4& c) {
    const float v0 = __uint_as_float(c.x << 16);
    const float v1 = __uint_as_float(c.x & 0xffff0000u);
    const float v2 = __uint_as_float(c.y << 16);
    const float v3 = __uint_as_float(c.y & 0xffff0000u);
    const float v4 = __uint_as_float(c.z << 16);
    const float v5 = __uint_as_float(c.z & 0xffff0000u);
    const float v6 = __uint_as_float(c.w << 16);
    const float v7 = __uint_as_float(c.w & 0xffff0000u);
    return q0.x * v0 + q0.y * v1 + q0.z * v2 + q0.w * v3
         + q1.x * v4 + q1.y * v5 + q1.z * v6 + q1.w * v7;
}

// ---- K1: fused convert (V->bf16) + prefilter (per-(slice,b) lists) ---------
__global__ __launch_bounds__(256) void prep_kernel(
    const float* __restrict__ V, const int* __restrict__ items,
    unsigned short* __restrict__ Vh, int* __restrict__ lists,
    int* __restrict__ counts) {
    const int blk = blockIdx.x;
    if (blk < CONV_BLOCKS) {
        const int i = blk * 256 + threadIdx.x;
        const float4* src = reinterpret_cast<const float4*>(V) + (size_t)i * 2;
        const float4 a = src[0];
        const float4 b = src[1];
        union { unsigned short h[8]; uint4 u; } pk;
        pk.h[0] = f2bf(a.x); pk.h[1] = f2bf(a.y); pk.h[2] = f2bf(a.z); pk.h[3] = f2bf(a.w);
        pk.h[4] = f2bf(b.x); pk.h[5] = f2bf(b.y); pk.h[6] = f2bf(b.z); pk.h[7] = f2bf(b.w);
        reinterpret_cast<uint4*>(Vh)[i] = pk.u;
    } else {
        const int b = blk - CONV_BLOCKS;
        __shared__ int cnt[NSLICE];
        const int t = threadIdx.x;
        if (t < NSLICE) cnt[t] = 0;
        __syncthreads();
        if (t < KITEMS) {
            const int it = items[(size_t)b * KITEMS + t];
            const int s = it / SLICE_ROWS;             // compile-time divisor
            const int pos = atomicAdd(&cnt[s], 1);     // order nondet; values invariant
            lists[((size_t)s * BATCH + b) * CAP + pos] = (it << 8) | t;
        }
        __syncthreads();
        if (t < NSLICE) counts[(size_t)t * BATCH + b] = cnt[t];
    }
}

// ---- K2: main — wave per (slice,b), registers-only list, bf16 gather -------
__global__ __launch_bounds__(256, 8) void main_lean_kernel(
    const float* __restrict__ seq,           // [BATCH, DIM] fp32
    const unsigned short* __restrict__ Vh,   // [NITEMS, DIM] bf16
    const float* __restrict__ Bias,          // [NITEMS]
    const int* __restrict__ lists,
    const int* __restrict__ counts,
    float* __restrict__ out)                 // [BATCH, KITEMS]
{
    const unsigned bid = blockIdx.x;
    const int s = bid & 7;       // slice == XCD id under round-robin dispatch (heuristic)
    const int g = bid >> 3;      // 0..1023
    const int tid  = threadIdx.x;
    const int lane = tid & 63;
    const int wv   = tid >> 6;   // wave -> which b
    const int sub  = lane & 15;  // lane within quad
    const int qd   = lane >> 4;  // quad -> item slot
    const int b    = g * 4 + wv;

    const size_t ub = (size_t)s * BATCH + b;
    const int* listg = lists + ub * CAP;
    const int e_reg = listg[lane];           // CAP>64: always in-bounds; stale
                                             // entries beyond n are never used
    const int n = counts[ub];
    if (n == 0) return;
    const int m = (n < 64) ? n : 64;

    const float4* seqr = reinterpret_cast<const float4*>(seq + (size_t)b * DIM);
    const float4 q0 = seqr[2 * sub];
    const float4 q1 = seqr[2 * sub + 1];
    float* outb = out + (size_t)b * KITEMS;

    int t = 0;
    // main: 8 items in flight (4 quads x unroll 2)
    for (; t + 8 <= m; t += 8) {
        const int eA = __shfl(e_reg, t + qd);
        const int eB = __shfl(e_reg, t + 4 + qd);
        const int itA = eA >> 8, kA = eA & 0xff;
        const int itB = eB >> 8, kB = eB & 0xff;

        const uint4 cA = reinterpret_cast<const uint4*>(Vh + (size_t)itA * DIM)[sub];
        const uint4 cB = reinterpret_cast<const uint4*>(Vh + (size_t)itB * DIM)[sub];
        float pA = dot_bf16(q0, q1, cA);
        float pB = dot_bf16(q0, q1, cB);

        pA += __shfl_xor(pA, 1);  pB += __shfl_xor(pB, 1);
        pA += __shfl_xor(pA, 2);  pB += __shfl_xor(pB, 2);
        pA += __shfl_xor(pA, 4);  pB += __shfl_xor(pB, 4);
        pA += __shfl_xor(pA, 8);  pB += __shfl_xor(pB, 8);

        if (sub == 0) {                       // 1 bias addr + 1 store addr per item
            outb[kA] = pA + Bias[itA];
            outb[kB] = pB + Bias[itB];
        }
    }
    // tail within first 64 entries
    for (; t < m; t += 4) {
        const int i = t + qd;
        const bool act = i < m;
        const int e = __shfl(e_reg, act ? i : (m - 1));
        const int it = e >> 8, k = e & 0xff;
        const uint4 c = reinterpret_cast<const uint4*>(Vh + (size_t)it * DIM)[sub];
        float p = dot_bf16(q0, q1, c);
        p += __shfl_xor(p, 1);
        p += __shfl_xor(p, 2);
        p += __shfl_xor(p, 4);
        p += __shfl_xor(p, 8);
        if (act && sub == 0) outb[k] = p + Bias[it];
    }
    // rare: n > 64 (binomial(200,1/8) ~ 8-sigma event, but must be correct)
    for (; t < n; t += 4) {
        const int i = t + qd;
        const bool act = i < n;
        const int e = listg[act ? i : (n - 1)];
        const int it = e >> 8, k = e & 0xff;
        const uint4 c = reinterpret_cast<const uint4*>(Vh + (size_t)it * DIM)[sub];
        float p = dot_bf16(q0, q1, c);
        p += __shfl_xor(p, 1);
        p += __shfl_xor(p, 2);
        p += __shfl_xor(p, 4);
        p += __shfl_xor(p, 8);
        if (act && sub == 0) outb[k] = p + Bias[it];
    }
}

// ---- fallback (ws too small): r9 fp32 kernel with in-kernel ballot filter --
__global__ __launch_bounds__(256, 8) void fallback_kernel(
    const float* __restrict__ seq, const int* __restrict__ items,
    const float* __restrict__ V, const float* __restrict__ Bias,
    float* __restrict__ out)
{
    const unsigned bid = blockIdx.x;
    const int s = bid & 7;
    const int g = bid >> 3;
    const int lo = s * SLICE_ROWS, hi = lo + SLICE_ROWS;
    const int tid  = threadIdx.x;
    const int lane = tid & 63;
    const int wv   = tid >> 6;
    const int sub  = lane & 15;
    const int qd   = lane >> 4;
    const int b    = g * 4 + wv;

    __shared__ int s_list[4][CAP];
    const int* itb = items + (size_t)b * KITEMS;
    int n = 0;
    #pragma unroll
    for (int r = 0; r < 4; ++r) {
        const int k = r * 64 + lane;
        int it = 0;
        bool pred = false;
        if (k < KITEMS) { it = itb[k]; pred = (it >= lo) & (it < hi); }
        const unsigned long long bal = __ballot(pred);
        if (pred) s_list[wv][n + __popcll(bal & ((1ull << lane) - 1ull))] = (it << 8) | k;
        n += __popcll(bal);
    }
    if (n == 0) return;

    const float4* seqr = reinterpret_cast<const float4*>(seq + (size_t)b * DIM);
    const float4 q0 = seqr[2 * sub];
    const float4 q1 = seqr[2 * sub + 1];
    float* outb = out + (size_t)b * KITEMS;

    for (int t = 0; t < n; t += 4) {
        const int i = t + qd;
        const bool act = i < n;
        const int e = s_list[wv][act ? i : (n - 1)];
        const int it = e >> 8, k = e & 0xff;
        const float4* vr = reinterpret_cast<const float4*>(V + (size_t)it * DIM);
        const float4 a0 = vr[2 * sub], a1 = vr[2 * sub + 1];
        float p = q0.x*a0.x + q0.y*a0.y + q0.z*a0.z + q0.w*a0.w
                + q1.x*a1.x + q1.y*a1.y + q1.z*a1.z + q1.w*a1.w;
        p += __shfl_xor(p, 1);
        p += __shfl_xor(p, 2);
        p += __shfl_xor(p, 4);
        p += __shfl_xor(p, 8);
        if (act && sub == 0) outb[k] = p + Bias[it];
    }
}

extern "C" void kernel_launch(void* const* d_in, const int* in_sizes, int n_in,
                              void* d_out, int out_size, void* d_ws, size_t ws_size,
                              hipStream_t stream) {
    const float* seq   = (const float*)d_in[0];
    const int*   items = (const int*)d_in[1];
    const float* V     = (const float*)d_in[2];
    const float* Bias  = (const float*)d_in[3];
    float*       out   = (float*)d_out;

    const size_t vh_bytes     = (size_t)NITEMS * DIM * 2;           // 25,600,000
    const size_t lists_bytes  = (size_t)NSLICE * BATCH * CAP * 4;   // 27,262,976
    const size_t counts_bytes = (size_t)NSLICE * BATCH * 4;         //    131,072
    const size_t need = vh_bytes + lists_bytes + counts_bytes;
    const int grid_main = (BATCH / 4) * NSLICE;                     // 8192

    if (ws_size >= need) {
        char* ws = (char*)d_ws;
        unsigned short* Vh    = (unsigned short*)ws;
        int*            lists = (int*)(ws + vh_bytes);
        int*            counts= (int*)(ws + vh_bytes + lists_bytes);
        prep_kernel<<<dim3(PREP_BLOCKS), dim3(256), 0, stream>>>(V, items, Vh, lists, counts);
        main_lean_kernel<<<dim3(grid_main), dim3(256), 0, stream>>>(seq, Vh, Bias, lists, counts, out);
    } else {
        fallback_kernel<<<dim3(grid_main), dim3(256), 0, stream>>>(seq, items, V, Bias, out);
    }
}

// Round 11
// 39.862 us; speedup vs baseline: 2.2999x; 1.1276x over previous
//
#include <hip/hip_runtime.h>

// DenseByItems: out[b,k] = dot(V[items[b,k]], seq[b]) + B[items[b,k]]
// seq: [4096,128] f32, items: [4096,200] i32, V: [100000,128] f32, B: [100000,1] f32
//
// Round 11: halve the gather address count (the measured wall: ~0.65
// lane-addrs/cy/CU across 5 structures). V quantized to int8 + per-row f32
// scale (row = 128 B = 8 lane-loads vs bf16's 16). Dequant deferred to after
// the 8-lane reduction (writer lane only). Prefilter lists + XCD slicing kept.

#define BATCH 4096
#define KITEMS 200
#define DIM 128
#define NITEMS 100000
#define NSLICE 8
#define SLICE_ROWS (NITEMS / NSLICE)   // 12500
#define CAP 208
#define QROWS_PB 16                    // rows quantized per block (16-lane group each)
#define QCONV_BLOCKS (NITEMS / QROWS_PB)       // 6250
#define PREP_BLOCKS (QCONV_BLOCKS + BATCH)     // fused grid

// ---- K1: fused per-row int8 quantize + per-(slice,b) prefilter -------------
__global__ __launch_bounds__(256) void prep_kernel(
    const float* __restrict__ V, const int* __restrict__ items,
    signed char* __restrict__ Q8, float* __restrict__ scales,
    int* __restrict__ lists, int* __restrict__ counts)
{
    const int blk = blockIdx.x;
    const int tid = threadIdx.x;
    if (blk < QCONV_BLOCKS) {
        // one row per 16-lane group; block covers 16 consecutive rows (8 KB)
        const int grp = tid >> 4;
        const int l16 = tid & 15;
        const int row = blk * QROWS_PB + grp;
        const float4* vr = reinterpret_cast<const float4*>(V + (size_t)row * DIM);
        const float4 a = vr[l16 * 2];
        const float4 b = vr[l16 * 2 + 1];
        float m = fmaxf(fmaxf(fmaxf(fabsf(a.x), fabsf(a.y)), fmaxf(fabsf(a.z), fabsf(a.w))),
                        fmaxf(fmaxf(fabsf(b.x), fabsf(b.y)), fmaxf(fabsf(b.z), fabsf(b.w))));
        m = fmaxf(m, __shfl_xor(m, 1));
        m = fmaxf(m, __shfl_xor(m, 2));
        m = fmaxf(m, __shfl_xor(m, 4));
        m = fmaxf(m, __shfl_xor(m, 8));
        m = fmaxf(m, 1e-20f);
        const float inv = 127.0f / m;
        int q[8];
        q[0] = (int)__builtin_rintf(a.x * inv);
        q[1] = (int)__builtin_rintf(a.y * inv);
        q[2] = (int)__builtin_rintf(a.z * inv);
        q[3] = (int)__builtin_rintf(a.w * inv);
        q[4] = (int)__builtin_rintf(b.x * inv);
        q[5] = (int)__builtin_rintf(b.y * inv);
        q[6] = (int)__builtin_rintf(b.z * inv);
        q[7] = (int)__builtin_rintf(b.w * inv);
        uint2 pk;
        pk.x = (unsigned)(q[0] & 0xff) | ((unsigned)(q[1] & 0xff) << 8)
             | ((unsigned)(q[2] & 0xff) << 16) | ((unsigned)(q[3] & 0xff) << 24);
        pk.y = (unsigned)(q[4] & 0xff) | ((unsigned)(q[5] & 0xff) << 8)
             | ((unsigned)(q[6] & 0xff) << 16) | ((unsigned)(q[7] & 0xff) << 24);
        *reinterpret_cast<uint2*>(Q8 + (size_t)row * DIM + l16 * 8) = pk;
        if (l16 == 0) scales[row] = m * (1.0f / 127.0f);
    } else {
        const int b = blk - QCONV_BLOCKS;
        __shared__ int cnt[NSLICE];
        if (tid < NSLICE) cnt[tid] = 0;
        __syncthreads();
        if (tid < KITEMS) {
            const int it = items[(size_t)b * KITEMS + tid];
            const int s = it / SLICE_ROWS;             // compile-time divisor
            const int pos = atomicAdd(&cnt[s], 1);     // order nondet; values invariant
            lists[((size_t)s * BATCH + b) * CAP + pos] = (it << 8) | tid;
        }
        __syncthreads();
        if (tid < NSLICE) counts[(size_t)tid * BATCH + b] = cnt[tid];
    }
}

__device__ __forceinline__ float i8f(unsigned w, int j) {
    return (float)((signed char)((w >> (j * 8)) & 0xffu));
}

__device__ __forceinline__ float dotq(const float4& q0, const float4& q1,
                                      const float4& q2, const float4& q3,
                                      const uint4& c) {
    return q0.x * i8f(c.x, 0) + q0.y * i8f(c.x, 1) + q0.z * i8f(c.x, 2) + q0.w * i8f(c.x, 3)
         + q1.x * i8f(c.y, 0) + q1.y * i8f(c.y, 1) + q1.z * i8f(c.y, 2) + q1.w * i8f(c.y, 3)
         + q2.x * i8f(c.z, 0) + q2.y * i8f(c.z, 1) + q2.z * i8f(c.z, 2) + q2.w * i8f(c.z, 3)
         + q3.x * i8f(c.w, 0) + q3.y * i8f(c.w, 1) + q3.z * i8f(c.w, 2) + q3.w * i8f(c.w, 3);
}

// ---- K2: main — wave per (slice,b); 8 lanes/item; int8 gather --------------
__global__ __launch_bounds__(256, 8) void main_q8_kernel(
    const float* __restrict__ seq,          // [BATCH, DIM] fp32
    const signed char* __restrict__ Q8,     // [NITEMS, DIM] int8
    const float* __restrict__ scales,       // [NITEMS]
    const float* __restrict__ Bias,         // [NITEMS]
    const int* __restrict__ lists,
    const int* __restrict__ counts,
    float* __restrict__ out)                // [BATCH, KITEMS]
{
    const unsigned bid = blockIdx.x;
    const int s = bid & 7;       // slice == XCD id under round-robin dispatch (heuristic)
    const int g = bid >> 3;
    const int tid  = threadIdx.x;
    const int lane = tid & 63;
    const int wv   = tid >> 6;   // wave -> which b
    const int sub8 = lane & 7;   // lane within its 8-lane item-group
    const int oct  = lane >> 3;  // 0..7 -> item slot
    const int b    = g * 4 + wv;

    const size_t ub = (size_t)s * BATCH + b;
    const int* listg = lists + ub * CAP;
    const int e_reg = listg[lane];           // entries beyond n never used
    const int n = counts[ub];
    if (n == 0) return;
    const int m = (n < 64) ? n : 64;

    // lane owns seq elements [sub8*16, sub8*16+16)
    const float4* seqr = reinterpret_cast<const float4*>(seq + (size_t)b * DIM);
    const float4 q0 = seqr[sub8 * 4 + 0];
    const float4 q1 = seqr[sub8 * 4 + 1];
    const float4 q2 = seqr[sub8 * 4 + 2];
    const float4 q3 = seqr[sub8 * 4 + 3];
    float* outb = out + (size_t)b * KITEMS;

    int t = 0;
    // main: 16 items in flight per wave (8 octs x unroll 2)
    for (; t + 16 <= m; t += 16) {
        const int eA = __shfl(e_reg, t + oct);
        const int eB = __shfl(e_reg, t + 8 + oct);
        const int itA = eA >> 8, kA = eA & 0xff;
        const int itB = eB >> 8, kB = eB & 0xff;

        const uint4 cA = *reinterpret_cast<const uint4*>(Q8 + (size_t)itA * DIM + sub8 * 16);
        const uint4 cB = *reinterpret_cast<const uint4*>(Q8 + (size_t)itB * DIM + sub8 * 16);
        float pA = dotq(q0, q1, q2, q3, cA);
        float pB = dotq(q0, q1, q2, q3, cB);

        pA += __shfl_xor(pA, 1);  pB += __shfl_xor(pB, 1);
        pA += __shfl_xor(pA, 2);  pB += __shfl_xor(pB, 2);
        pA += __shfl_xor(pA, 4);  pB += __shfl_xor(pB, 4);

        if (sub8 == 0) {
            outb[kA] = pA * scales[itA] + Bias[itA];
            outb[kB] = pB * scales[itB] + Bias[itB];
        }
    }
    // tail within first 64 entries
    for (; t < m; t += 8) {
        const int i = t + oct;
        const bool act = i < m;
        const int e = __shfl(e_reg, act ? i : (m - 1));
        const int it = e >> 8, k = e & 0xff;
        const uint4 c = *reinterpret_cast<const uint4*>(Q8 + (size_t)it * DIM + sub8 * 16);
        float p = dotq(q0, q1, q2, q3, c);
        p += __shfl_xor(p, 1);
        p += __shfl_xor(p, 2);
        p += __shfl_xor(p, 4);
        if (act && sub8 == 0) outb[k] = p * scales[it] + Bias[it];
    }
    // rare: n > 64 (must stay correct)
    for (; t < n; t += 8) {
        const int i = t + oct;
        const bool act = i < n;
        const int e = listg[act ? i : (n - 1)];
        const int it = e >> 8, k = e & 0xff;
        const uint4 c = *reinterpret_cast<const uint4*>(Q8 + (size_t)it * DIM + sub8 * 16);
        float p = dotq(q0, q1, q2, q3, c);
        p += __shfl_xor(p, 1);
        p += __shfl_xor(p, 2);
        p += __shfl_xor(p, 4);
        if (act && sub8 == 0) outb[k] = p * scales[it] + Bias[it];
    }
}

// ---- fallback (ws too small): fp32 sliced kernel with ballot filter --------
__global__ __launch_bounds__(256, 8) void fallback_kernel(
    const float* __restrict__ seq, const int* __restrict__ items,
    const float* __restrict__ V, const float* __restrict__ Bias,
    float* __restrict__ out)
{
    const unsigned bid = blockIdx.x;
    const int s = bid & 7;
    const int g = bid >> 3;
    const int lo = s * SLICE_ROWS, hi = lo + SLICE_ROWS;
    const int tid  = threadIdx.x;
    const int lane = tid & 63;
    const int wv   = tid >> 6;
    const int sub  = lane & 15;
    const int qd   = lane >> 4;
    const int b    = g * 4 + wv;

    __shared__ int s_list[4][CAP];
    const int* itb = items + (size_t)b * KITEMS;
    int n = 0;
    #pragma unroll
    for (int r = 0; r < 4; ++r) {
        const int k = r * 64 + lane;
        int it = 0;
        bool pred = false;
        if (k < KITEMS) { it = itb[k]; pred = (it >= lo) & (it < hi); }
        const unsigned long long bal = __ballot(pred);
        if (pred) s_list[wv][n + __popcll(bal & ((1ull << lane) - 1ull))] = (it << 8) | k;
        n += __popcll(bal);
    }
    if (n == 0) return;

    const float4* seqr = reinterpret_cast<const float4*>(seq + (size_t)b * DIM);
    const float4 q0 = seqr[2 * sub];
    const float4 q1 = seqr[2 * sub + 1];
    float* outb = out + (size_t)b * KITEMS;

    for (int t = 0; t < n; t += 4) {
        const int i = t + qd;
        const bool act = i < n;
        const int e = s_list[wv][act ? i : (n - 1)];
        const int it = e >> 8, k = e & 0xff;
        const float4* vr = reinterpret_cast<const float4*>(V + (size_t)it * DIM);
        const float4 a0 = vr[2 * sub], a1 = vr[2 * sub + 1];
        float p = q0.x*a0.x + q0.y*a0.y + q0.z*a0.z + q0.w*a0.w
                + q1.x*a1.x + q1.y*a1.y + q1.z*a1.z + q1.w*a1.w;
        p += __shfl_xor(p, 1);
        p += __shfl_xor(p, 2);
        p += __shfl_xor(p, 4);
        p += __shfl_xor(p, 8);
        if (act && sub == 0) outb[k] = p + Bias[it];
    }
}

extern "C" void kernel_launch(void* const* d_in, const int* in_sizes, int n_in,
                              void* d_out, int out_size, void* d_ws, size_t ws_size,
                              hipStream_t stream) {
    const float* seq   = (const float*)d_in[0];
    const int*   items = (const int*)d_in[1];
    const float* V     = (const float*)d_in[2];
    const float* Bias  = (const float*)d_in[3];
    float*       out   = (float*)d_out;

    const size_t q8_bytes     = (size_t)NITEMS * DIM;               // 12,800,000
    const size_t sc_bytes     = (size_t)NITEMS * 4;                 //    400,000
    const size_t pad          = (256 - (q8_bytes + sc_bytes) % 256) % 256;
    const size_t lists_bytes  = (size_t)NSLICE * BATCH * CAP * 4;   // 27,262,976
    const size_t counts_bytes = (size_t)NSLICE * BATCH * 4;         //    131,072
    const size_t need = q8_bytes + sc_bytes + pad + lists_bytes + counts_bytes;
    const int grid_main = (BATCH / 4) * NSLICE;                     // 8192

    if (ws_size >= need) {
        char* ws = (char*)d_ws;
        signed char* Q8     = (signed char*)ws;
        float*       scales = (float*)(ws + q8_bytes);
        int*         lists  = (int*)(ws + q8_bytes + sc_bytes + pad);
        int*         counts = (int*)(ws + q8_bytes + sc_bytes + pad + lists_bytes);
        prep_kernel<<<dim3(PREP_BLOCKS), dim3(256), 0, stream>>>(V, items, Q8, scales, lists, counts);
        main_q8_kernel<<<dim3(grid_main), dim3(256), 0, stream>>>(seq, Q8, scales, Bias, lists, counts, out);
    } else {
        fallback_kernel<<<dim3(grid_main), dim3(256), 0, stream>>>(seq, items, V, Bias, out);
    }
}

// Round 12
// 35.140 us; speedup vs baseline: 2.6089x; 1.1344x over previous
//
#include <hip/hip_runtime.h>

// DenseByItems: out[b,k] = dot(V[items[b,k]], seq[b]) + B[items[b,k]]
// seq: [4096,128] f32, items: [4096,200] i32, V: [100000,128] f32, B: [100000,1] f32
//
// Round 12: address-count minimization, final form under the measured wall
// (~0.55-0.68 lane-addrs/cy/CU, identical across sliced-L2 and unsliced-L3
// paths -> slicing/prefilter machinery removed entirely).
//  - prep: V -> int8 rows + fused (scale,bias) float2 table
//  - main: 2 waves per b; item ids in 2 regs + __shfl broadcast; 8 lanes/item
//    (128 B int8 row = 8 x 16 B); writer-lane-only SB load + store.
// Addrs/item ~= 8 (V) + 1 (items) + 1 (SB) + 1 (out) + 0.3 (seq) ~= 11.3.

#define BATCH 4096
#define KITEMS 200
#define DIM 128
#define NITEMS 100000
#define QROWS_PB 16
#define QCONV_BLOCKS (NITEMS / QROWS_PB)   // 6250

// ---- K1: per-row int8 quantize + (scale,bias) pack -------------------------
__global__ __launch_bounds__(256) void prep_kernel(
    const float* __restrict__ V, const float* __restrict__ Bias,
    signed char* __restrict__ Q8, float2* __restrict__ SB)
{
    const int tid = threadIdx.x;
    const int grp = tid >> 4;          // 16-lane group -> one row
    const int l16 = tid & 15;
    const int row = blockIdx.x * QROWS_PB + grp;
    const float4* vr = reinterpret_cast<const float4*>(V + (size_t)row * DIM);
    const float4 a = vr[l16 * 2];
    const float4 b = vr[l16 * 2 + 1];
    float m = fmaxf(fmaxf(fmaxf(fabsf(a.x), fabsf(a.y)), fmaxf(fabsf(a.z), fabsf(a.w))),
                    fmaxf(fmaxf(fabsf(b.x), fabsf(b.y)), fmaxf(fabsf(b.z), fabsf(b.w))));
    m = fmaxf(m, __shfl_xor(m, 1));
    m = fmaxf(m, __shfl_xor(m, 2));
    m = fmaxf(m, __shfl_xor(m, 4));
    m = fmaxf(m, __shfl_xor(m, 8));
    m = fmaxf(m, 1e-20f);
    const float inv = 127.0f / m;
    int q[8];
    q[0] = (int)__builtin_rintf(a.x * inv);
    q[1] = (int)__builtin_rintf(a.y * inv);
    q[2] = (int)__builtin_rintf(a.z * inv);
    q[3] = (int)__builtin_rintf(a.w * inv);
    q[4] = (int)__builtin_rintf(b.x * inv);
    q[5] = (int)__builtin_rintf(b.y * inv);
    q[6] = (int)__builtin_rintf(b.z * inv);
    q[7] = (int)__builtin_rintf(b.w * inv);
    uint2 pk;
    pk.x = (unsigned)(q[0] & 0xff) | ((unsigned)(q[1] & 0xff) << 8)
         | ((unsigned)(q[2] & 0xff) << 16) | ((unsigned)(q[3] & 0xff) << 24);
    pk.y = (unsigned)(q[4] & 0xff) | ((unsigned)(q[5] & 0xff) << 8)
         | ((unsigned)(q[6] & 0xff) << 16) | ((unsigned)(q[7] & 0xff) << 24);
    *reinterpret_cast<uint2*>(Q8 + (size_t)row * DIM + l16 * 8) = pk;
    if (l16 == 0) SB[row] = make_float2(m * (1.0f / 127.0f), Bias[row]);
}

__device__ __forceinline__ float i8f(unsigned w, int j) {
    return (float)((signed char)((w >> (j * 8)) & 0xffu));
}

__device__ __forceinline__ float dotq(const float4& q0, const float4& q1,
                                      const float4& q2, const float4& q3,
                                      const uint4& c) {
    return q0.x * i8f(c.x, 0) + q0.y * i8f(c.x, 1) + q0.z * i8f(c.x, 2) + q0.w * i8f(c.x, 3)
         + q1.x * i8f(c.y, 0) + q1.y * i8f(c.y, 1) + q1.z * i8f(c.y, 2) + q1.w * i8f(c.y, 3)
         + q2.x * i8f(c.z, 0) + q2.y * i8f(c.z, 1) + q2.z * i8f(c.z, 2) + q2.w * i8f(c.z, 3)
         + q3.x * i8f(c.w, 0) + q3.y * i8f(c.w, 1) + q3.z * i8f(c.w, 2) + q3.w * i8f(c.w, 3);
}

// ---- K2: main — 2 waves per b, register item list, int8 gather -------------
__global__ __launch_bounds__(256, 8) void main_q8_kernel(
    const float* __restrict__ seq,          // [BATCH, DIM] fp32
    const int* __restrict__ items,          // [BATCH, KITEMS]
    const signed char* __restrict__ Q8,     // [NITEMS, DIM] int8
    const float2* __restrict__ SB,          // [NITEMS] (scale, bias)
    float* __restrict__ out)                // [BATCH, KITEMS]
{
    const int g    = blockIdx.x;            // 0..2047
    const int tid  = threadIdx.x;
    const int lane = tid & 63;
    const int wv   = tid >> 6;
    const int b    = g * 2 + (wv >> 1);     // 2 b's per block
    const int half = wv & 1;                // which 100 items of this b
    const int sub8 = lane & 7;              // lane within 8-lane item-group
    const int oct  = lane >> 3;             // item slot 0..7

    // This wave's 100 item ids in 2 registers (coalesced load, 1 addr/item).
    const int* itb = items + (size_t)b * KITEMS + half * 100;
    const int i0 = itb[lane];                               // local 0..63
    const int i1 = (lane < 36) ? itb[64 + lane] : 0;        // local 64..99

    // lane owns seq elements [sub8*16, sub8*16+16)
    const float4* seqr = reinterpret_cast<const float4*>(seq + (size_t)b * DIM);
    const float4 q0 = seqr[sub8 * 4 + 0];
    const float4 q1 = seqr[sub8 * 4 + 1];
    const float4 q2 = seqr[sub8 * 4 + 2];
    const float4 q3 = seqr[sub8 * 4 + 3];
    float* outb = out + (size_t)b * KITEMS + half * 100;

    // phase A: local items 0..63 (4 iters x 16 items in flight)
    #pragma unroll
    for (int u = 0; u < 4; ++u) {
        const int jA = u * 16 + oct;
        const int jB = jA + 8;
        const int itA = __shfl(i0, jA);
        const int itB = __shfl(i0, jB);
        const uint4 cA = *reinterpret_cast<const uint4*>(Q8 + (size_t)itA * DIM + sub8 * 16);
        const uint4 cB = *reinterpret_cast<const uint4*>(Q8 + (size_t)itB * DIM + sub8 * 16);
        float pA = dotq(q0, q1, q2, q3, cA);
        float pB = dotq(q0, q1, q2, q3, cB);
        pA += __shfl_xor(pA, 1);  pB += __shfl_xor(pB, 1);
        pA += __shfl_xor(pA, 2);  pB += __shfl_xor(pB, 2);
        pA += __shfl_xor(pA, 4);  pB += __shfl_xor(pB, 4);
        if (sub8 == 0) {
            const float2 sA = SB[itA];
            const float2 sB_ = SB[itB];
            outb[jA] = pA * sA.x + sA.y;
            outb[jB] = pB * sB_.x + sB_.y;
        }
    }
    // phase B: local items 64..95 (2 iters x 16)
    #pragma unroll
    for (int u = 0; u < 2; ++u) {
        const int jA = u * 16 + oct;
        const int jB = jA + 8;
        const int itA = __shfl(i1, jA);
        const int itB = __shfl(i1, jB);
        const uint4 cA = *reinterpret_cast<const uint4*>(Q8 + (size_t)itA * DIM + sub8 * 16);
        const uint4 cB = *reinterpret_cast<const uint4*>(Q8 + (size_t)itB * DIM + sub8 * 16);
        float pA = dotq(q0, q1, q2, q3, cA);
        float pB = dotq(q0, q1, q2, q3, cB);
        pA += __shfl_xor(pA, 1);  pB += __shfl_xor(pB, 1);
        pA += __shfl_xor(pA, 2);  pB += __shfl_xor(pB, 2);
        pA += __shfl_xor(pA, 4);  pB += __shfl_xor(pB, 4);
        if (sub8 == 0) {
            const float2 sA = SB[itA];
            const float2 sB_ = SB[itB];
            outb[64 + jA] = pA * sA.x + sA.y;
            outb[64 + jB] = pB * sB_.x + sB_.y;
        }
    }
    // tail: local items 96..99 (octs 0..3 write; 4..7 duplicate addresses)
    {
        const int itT = __shfl(i1, 32 + (oct & 3));
        const uint4 c = *reinterpret_cast<const uint4*>(Q8 + (size_t)itT * DIM + sub8 * 16);
        float p = dotq(q0, q1, q2, q3, c);
        p += __shfl_xor(p, 1);
        p += __shfl_xor(p, 2);
        p += __shfl_xor(p, 4);
        if (oct < 4 && sub8 == 0) {
            const float2 sT = SB[itT];
            outb[96 + oct] = p * sT.x + sT.y;
        }
    }
}

// ---- fallback (ws too small): direct fp32 ----------------------------------
__global__ __launch_bounds__(256, 4) void fallback_kernel(
    const float* __restrict__ seq, const int* __restrict__ items,
    const float* __restrict__ V, const float* __restrict__ Bias,
    float* __restrict__ out)
{
    const int b    = blockIdx.x;
    const int tid  = threadIdx.x;
    const int lane = tid & 63;
    const int wave = tid >> 6;
    const int sub  = lane & 15;
    const int grp  = lane >> 4;

    __shared__ int s_items[KITEMS];
    if (tid < KITEMS) s_items[tid] = items[(size_t)b * KITEMS + tid];
    __syncthreads();

    const float4* seq4 = reinterpret_cast<const float4*>(seq + (size_t)b * DIM);
    const float4 s0 = seq4[sub];
    const float4 s1 = seq4[sub + 16];

    for (int k0 = wave * 4; k0 < KITEMS; k0 += 16) {
        const int k = k0 + grp;
        float p = 0.0f;
        int item = 0;
        const bool active = (k < KITEMS);
        if (active) {
            item = s_items[k];
            const float4* v4 = reinterpret_cast<const float4*>(V + (size_t)item * DIM);
            const float4 v0 = v4[sub];
            const float4 v1 = v4[sub + 16];
            p = s0.x * v0.x + s0.y * v0.y + s0.z * v0.z + s0.w * v0.w
              + s1.x * v1.x + s1.y * v1.y + s1.z * v1.z + s1.w * v1.w;
        }
        p += __shfl_xor(p, 1);
        p += __shfl_xor(p, 2);
        p += __shfl_xor(p, 4);
        p += __shfl_xor(p, 8);
        if (active && sub == 0) out[(size_t)b * KITEMS + k] = p + Bias[item];
    }
}

extern "C" void kernel_launch(void* const* d_in, const int* in_sizes, int n_in,
                              void* d_out, int out_size, void* d_ws, size_t ws_size,
                              hipStream_t stream) {
    const float* seq   = (const float*)d_in[0];
    const int*   items = (const int*)d_in[1];
    const float* V     = (const float*)d_in[2];
    const float* Bias  = (const float*)d_in[3];
    float*       out   = (float*)d_out;

    const size_t q8_bytes = (size_t)NITEMS * DIM;        // 12,800,000
    const size_t pad      = (8 - q8_bytes % 8) % 8;
    const size_t sb_bytes = (size_t)NITEMS * 8;          //    800,000
    const size_t need = q8_bytes + pad + sb_bytes;

    if (ws_size >= need) {
        signed char* Q8 = (signed char*)d_ws;
        float2*      SB = (float2*)((char*)d_ws + q8_bytes + pad);
        prep_kernel<<<dim3(QCONV_BLOCKS), dim3(256), 0, stream>>>(V, Bias, Q8, SB);
        main_q8_kernel<<<dim3(BATCH / 2), dim3(256), 0, stream>>>(seq, items, Q8, SB, out);
    } else {
        fallback_kernel<<<dim3(BATCH), dim3(256), 0, stream>>>(seq, items, V, Bias, out);
    }
}